// Round 7
// baseline (394.453 us; speedup 1.0000x reference)
//
#include <hip/hip_runtime.h>
#include <hip/hip_bf16.h>

// Problem constants (from reference)
#define N_NODES 100000
#define N_EDGES 1600000
#define N_RELS  8
#define IN_F    64
#define HID_F   64
#define OUT_F   32
#define NSEG    (N_NODES * N_RELS)      // 800000 (node, rel) segments
#define SCAN_EPB 1024                   // elements per scan block (256 thr x 4)
#define SCAN_NB  ((NSEG + SCAN_EPB - 1) / SCAN_EPB)  // 782
#define NTILES  (N_NODES / 16)          // 6250
#define LGRID   1024                    // persistent layer grid

typedef __attribute__((ext_vector_type(8))) short short8;   // 8 bf16 = 4 VGPRs
typedef __attribute__((ext_vector_type(4))) float f32x4;

__device__ __forceinline__ float b2f(unsigned short u) {
    return __uint_as_float(((unsigned)u) << 16);
}
__device__ __forceinline__ unsigned short f2b(float f) {
    unsigned u = __float_as_uint(f);
    u += 0x7FFFu + ((u >> 16) & 1u);      // RNE
    return (unsigned short)(u >> 16);
}

// Barrier that does NOT drain vmcnt: LDS ordering only. Keeps cross-tile
// global prefetches and output stores in flight (hipcc's __syncthreads
// emits s_waitcnt vmcnt(0) lgkmcnt(0) which would void the pipeline).
__device__ __forceinline__ void barrier_lgkm() {
    asm volatile("s_waitcnt lgkmcnt(0)" ::: "memory");
    __builtin_amdgcn_s_barrier();
}

#define PREP_W1 (576 * 64)
#define PREP_W2 (576 * 32)
#define PREP_CVT (N_NODES * 64 / 4)
#define PREP_TOT (PREP_W1 + PREP_W2 + PREP_CVT)

// ---------------------------------------------------------------------------
// 1) Histogram + rank (atomic-free scatter later), with prep work fused in.
// ---------------------------------------------------------------------------
__global__ void k_hist(const int* __restrict__ dst, const int* __restrict__ et,
                       int* __restrict__ cnt, int* __restrict__ rank,
                       const float* __restrict__ W1, const float* __restrict__ root1,
                       const float* __restrict__ W2, const float* __restrict__ root2,
                       const float* __restrict__ x,
                       ushort* __restrict__ Wt1b, ushort* __restrict__ Wt2b,
                       ushort* __restrict__ xb) {
    const int e = blockIdx.x * 256 + threadIdx.x;
    const int gsz = gridDim.x * 256;
    for (int j = e; j < PREP_TOT; j += gsz) {
        if (j < PREP_W1) {
            int o = j / 576, k = j - o * 576;
            float v = (k < 512) ? W1[k * 64 + o] : root1[(k - 512) * 64 + o];
            Wt1b[j] = f2b(v);
        } else if (j < PREP_W1 + PREP_W2) {
            int j2 = j - PREP_W1;
            int o = j2 / 576, k = j2 - o * 576;
            float v = (k < 512) ? W2[k * 32 + o] : root2[(k - 512) * 32 + o];
            Wt2b[j2] = f2b(v);
        } else {
            int j2 = j - PREP_W1 - PREP_W2;
            float4 v = *(const float4*)(x + (size_t)j2 * 4);
            ushort4 u;
            u.x = f2b(v.x); u.y = f2b(v.y); u.z = f2b(v.z); u.w = f2b(v.w);
            *(ushort4*)(xb + (size_t)j2 * 4) = u;
        }
    }
    if (e < N_EDGES) {
        int seg = dst[e] * N_RELS + et[e];
        rank[e] = atomicAdd(&cnt[seg], 1);
    }
}

// ---------------------------------------------------------------------------
// 2a) Scan pass A
// ---------------------------------------------------------------------------
__global__ void k_scanA(const int* __restrict__ cnt, int* __restrict__ bsums) {
    __shared__ int red[256];
    int t = threadIdx.x;
    int base = blockIdx.x * SCAN_EPB + t * 4;
    int s = 0;
    #pragma unroll
    for (int j = 0; j < 4; ++j) {
        int idx = base + j;
        if (idx < NSEG) s += cnt[idx];
    }
    red[t] = s;
    __syncthreads();
    for (int st = 128; st > 0; st >>= 1) {
        if (t < st) red[t] += red[t + st];
        __syncthreads();
    }
    if (t == 0) bsums[blockIdx.x] = red[0];
}

// ---------------------------------------------------------------------------
// 2b) Scan pass C
// ---------------------------------------------------------------------------
__global__ void k_scanC(const int* __restrict__ cnt, const int* __restrict__ bsums,
                        int* __restrict__ offs) {
    __shared__ int red[256];
    __shared__ int ts[256];
    int t = threadIdx.x;

    int partial = 0;
    #pragma unroll
    for (int jj = 0; jj < 4; ++jj) {
        int j = t + jj * 256;
        if (j < SCAN_NB && j < (int)blockIdx.x) partial += bsums[j];
    }
    red[t] = partial;
    __syncthreads();
    for (int st = 128; st > 0; st >>= 1) {
        if (t < st) red[t] += red[t + st];
        __syncthreads();
    }
    const int base0 = red[0];

    int base = blockIdx.x * SCAN_EPB + t * 4;
    int v[4];
    int local = 0;
    #pragma unroll
    for (int j = 0; j < 4; ++j) {
        int idx = base + j;
        v[j] = (idx < NSEG) ? cnt[idx] : 0;
        local += v[j];
    }
    ts[t] = local;
    __syncthreads();
    for (int off = 1; off < 256; off <<= 1) {
        int x = (t >= off) ? ts[t - off] : 0;
        __syncthreads();
        ts[t] += x;
        __syncthreads();
    }
    int run = base0 + (ts[t] - local);
    #pragma unroll
    for (int j = 0; j < 4; ++j) {
        int idx = base + j;
        if (idx < NSEG) offs[idx] = run;
        run += v[j];
    }
}

// ---------------------------------------------------------------------------
// 3) Pure scatter: ssrc[offs[seg]+rank] = (src<<8) | ((dst&15)<<4) | rel
// ---------------------------------------------------------------------------
__global__ void k_scat(const int* __restrict__ src, const int* __restrict__ dst,
                       const int* __restrict__ et, const int* __restrict__ offs,
                       const int* __restrict__ rank, int* __restrict__ ssrc) {
    int e = blockIdx.x * 256 + threadIdx.x;
    if (e < N_EDGES) {
        int r = et[e];
        int d = dst[e];
        int seg = d * N_RELS + r;
        ssrc[offs[seg] + rank[e]] = (src[e] << 8) | ((d & 15) << 4) | r;
    }
}

// ---------------------------------------------------------------------------
// First segment boundary >= p in [s,e), using a PREFETCHED window:
// wv = ssrc[p+f], wm = ssrc[p+f-1] (valid where p+f < e). Slow path (segment
// spanning >64: essentially never with this data) falls back to fresh loads.
// ---------------------------------------------------------------------------
__device__ __forceinline__ int seg_scan(const int* __restrict__ ssrc,
                                        int p, int s, int e, int f,
                                        int wv, int wm) {
    if (p <= s) return s;
    if (p >= e) return e;
    bool b = (p + f >= e) || (((wm ^ wv) & 255) != 0);
    unsigned long long msk = __ballot(b);
    if (msk) return p + (int)__builtin_ctzll(msk);
    int pp = p + 64;
    while (true) {
        int r = pp + f;
        bool bb;
        if (r >= e) bb = true;
        else bb = ((ssrc[r - 1] ^ ssrc[r]) & 255) != 0;
        unsigned long long mm = __ballot(bb);
        if (mm) return pp + (int)__builtin_ctzll(mm);
        pp += 64;
    }
}

// Per-16-edge batch: readlane->SGPR, 16 independent gathers, running-sum
// with uniform-scalar seg-boundary flush (plain ds_write, wave-exclusive).
#define BATCH16(PKREG)                                                        \
    do {                                                                      \
        int pv[16]; float xv[16];                                             \
        _Pragma("unroll")                                                     \
        for (int i = 0; i < 16; ++i)                                          \
            pv[i] = __builtin_amdgcn_readlane(PKREG, e + i);                  \
        _Pragma("unroll")                                                     \
        for (int i = 0; i < 16; ++i)                                          \
            xv[i] = b2f(xb[(size_t)((unsigned)pv[i] >> 8) * 64 + f]);         \
        _Pragma("unroll")                                                     \
        for (int i = 0; i < 16; ++i) {                                        \
            const int sg = pv[i] & 255;                                       \
            if (sg != pseg) {                                                 \
                if (pseg != 255) {                                            \
                    const int row = ((pseg >> 4) << 3) | (pseg & 7);          \
                    S32[row * 68 + f] = running;                              \
                }                                                             \
                running = 0.0f;                                               \
                pseg = sg;                                                    \
            }                                                                 \
            running += xv[i];                                                 \
        }                                                                     \
    } while (0)

// ---------------------------------------------------------------------------
// 4) Fused layer — PERSISTENT blocks + cross-tile pipeline (R7).
//    Grid = 1024 blocks, each loops ~6 tiles of 16 nodes.
//    R6 finding: layer2 @12.8MB fetch ran the same 100us as layer1 @86MB ->
//    NOT traffic-bound; per-tile serial latency chains dominate. Fixes:
//    (a) B-fragments persistent in registers (loaded once/block; was ~18
//        global loads inside the MFMA loop every tile, pipelined by 1);
//    (b) next tile's offs/cnt/root loads issue before this tile's MFMA;
//        next tile's stripe windows (= phase-1's FIRST DATA window, stripes
//        avg 32 < 64 edges) issue at tile tail -> phase 1 starts hot;
//    (c) barriers are lgkmcnt-only + raw s_barrier so prefetches/stores
//        stay in flight across them (syncthreads drains vmcnt(0)).
//    Per-edge path / flush / normalize / MFMA math identical to R6.
// ---------------------------------------------------------------------------
template <int NOUT, bool RELU, typename OutT>
__global__ __launch_bounds__(512, (NOUT == 64) ? 6 : 8) void k_layer(
        const ushort* __restrict__ xb, const int* __restrict__ offs,
        const int* __restrict__ cnt, const int* __restrict__ ssrc,
        const ushort* __restrict__ Wtb, const float* __restrict__ bias,
        OutT* __restrict__ out) {
    constexpr int NT = NOUT / 16;     // n-tiles
    constexpr int S  = 8 / NT;        // k-splits
    constexpr int MAXC = (NOUT == 64) ? 9 : 5;  // per-wave K-chunks
    __shared__ __align__(16) union {
        float  a32[128 * 68];         // (nib*8+rel) fp32 raw sums, stride 68
        ushort a16[16][584];          // bf16 A tiles (+root @512), 18688B
    } U;
    __shared__ float invT[128];

    float* S32 = U.a32;
    f32x4* pc = (f32x4*)((char*)&U + 18688);  // a32 tail; disjoint from a16

    const int tid = threadIdx.x;
    const int w = tid >> 6;
    const int f = tid & 63;

    // ---- wave roles ----
    const int t = w % NT, q = w / NT;
    constexpr int cbase = 18 / S, crem = 18 % S;
    const int cs = q * cbase + (q < crem ? q : crem);
    const int ce = cs + cbase + (q < crem ? 1 : 0);
    const int nc = ce - cs;
    const int n0 = t * 16;
    const ushort* bptr = Wtb + (n0 + (f & 15)) * 576 + ((f >> 4) * 8);

    // ---- persistent per-wave B fragments + bias (loaded once) ----
    short8 breg[MAXC];
    #pragma unroll
    for (int j = 0; j < MAXC; ++j)
        if (j < nc) breg[j] = *(const short8*)(bptr + (cs + j) * 32);
    const float bcol = bias[n0 + (f & 15)];
    const int m5 = tid >> 5, f2 = (tid & 31) * 2;

    // ---- first-tile metadata + stripe/window prefetch ----
    int tile = blockIdx.x;
    int startv = offs[tile * 128];
    int endv = (tile * 16 + 16 >= N_NODES) ? N_EDGES : offs[tile * 128 + 128];
    int cvp = (tid < 128) ? cnt[tile * 128 + tid] : 1;
    uint rootp = *(const uint*)(xb + (size_t)(tile * 16 + m5) * 64 + f2);

    int i0, i1, w0v, wm0, w1v, wm1;
    {
        const int tot = endv - startv;
        const int eb = tot >> 3, er = tot & 7;
        i0 = startv + w * eb + (w < er ? w : er);
        i1 = i0 + eb + (w < er ? 1 : 0);
        w0v = 0xFF; wm0 = 0; w1v = 0xFF; wm1 = 0;
        int r0 = i0 + f;
        if (r0 < endv) { w0v = ssrc[r0]; if (i0 > startv) wm0 = ssrc[r0 - 1]; }
        int r1 = i1 + f;
        if (r1 < endv && i1 < endv) { w1v = ssrc[r1]; if (i1 > startv) wm1 = ssrc[r1 - 1]; }
    }

    for (; tile < NTILES; tile += LGRID) {
        const int node0 = tile * 16;

        // ---- stripe bounds from prefetched windows (cheap ballots) ----
        const int bs = seg_scan(ssrc, i0, startv, endv, f, w0v, wm0);
        const int be = seg_scan(ssrc, i1, startv, endv, f, w1v, wm1);

        // ---- phase 0: zero fp32 region, invT from prefetched cnt ----
        {
            f32x4 z = (f32x4){0.0f, 0.0f, 0.0f, 0.0f};
            #pragma unroll
            for (int k = 0; k < 4; ++k)
                *(f32x4*)(S32 + (tid + k * 512) * 4) = z;
            S32[8192 + tid] = 0.0f;
            if (tid < 128) invT[tid] = 1.0f / (float)(cvp > 0 ? cvp : 1);
        }
        barrier_lgkm();

        // ---- phase 1: gathers; window 0 = prefetched w0v ----
        {
            float running = 0.0f;
            int pseg = 255;
            int pk = w0v;
            if (i0 + f < bs || i0 + f >= be) pk = 0xFF;   // mask to pad
            const int lim0 = (be - i0 < 64) ? (be - i0) : 64;
            const int eb0 = (bs - i0) & ~15;              // skip all-pad batches
            for (int e = eb0; e < lim0; e += 16) {
                BATCH16(pk);
            }
            for (int cb = i0 + 64; cb < be; cb += 64) {   // rare overflow path
                int n = be - cb; if (n > 64) n = 64;
                int pk2 = 0xFF;
                if (f < n && cb + f >= bs) pk2 = ssrc[cb + f];
                for (int e = 0; e < n; e += 16) {
                    BATCH16(pk2);
                }
            }
            if (pseg != 255) {
                const int row = ((pseg >> 4) << 3) | (pseg & 7);
                S32[row * 68 + f] = running;
            }
        }
        barrier_lgkm();

        // ---- phase 1.5a: read + normalize ----
        float rv[16];
        {
            const int row = tid >> 2;            // 0..127 (nib*8+rel)
            const int fb = (tid & 3) * 16;
            const float inv = invT[row];
            #pragma unroll
            for (int k = 0; k < 4; ++k) {
                f32x4 v = *(f32x4*)(S32 + row * 68 + fb + k * 4);
                rv[k * 4 + 0] = v.x * inv; rv[k * 4 + 1] = v.y * inv;
                rv[k * 4 + 2] = v.z * inv; rv[k * 4 + 3] = v.w * inv;
            }
        }
        barrier_lgkm();
        // ---- phase 1.5b: bf16 tiles + root row (prefetched reg) ----
        {
            const int row = tid >> 2;
            const int nib = row >> 3, rel = row & 7;
            const int fb = (tid & 3) * 16;
            ushort* dp = &U.a16[nib][rel * 64 + fb];
            short8 o0, o1;
            #pragma unroll
            for (int k = 0; k < 8; ++k) o0[k] = (short)f2b(rv[k]);
            #pragma unroll
            for (int k = 0; k < 8; ++k) o1[k] = (short)f2b(rv[8 + k]);
            *(short8*)dp = o0;
            *(short8*)(dp + 8) = o1;
            *(uint*)&U.a16[m5][512 + f2] = rootp;
        }

        // ---- next-tile metadata prefetch (hides under MFMA/phase 3) ----
        const int ntile = tile + LGRID;
        const bool more = ntile < NTILES;
        int nstart = 0, nend = 0, ncv = 1; uint nroot = 0;
        if (more) {
            nstart = offs[ntile * 128];
            nend = (ntile * 16 + 16 >= N_NODES) ? N_EDGES : offs[ntile * 128 + 128];
            ncv = (tid < 128) ? cnt[ntile * 128 + tid] : 1;
            nroot = *(const uint*)(xb + (size_t)(ntile * 16 + m5) * 64 + f2);
        }
        barrier_lgkm();

        // ---- phase 2: MFMA from persistent B registers ----
        f32x4 acc = (f32x4){0.0f, 0.0f, 0.0f, 0.0f};
        {
            const ushort* aptr = &U.a16[f & 15][(f >> 4) * 8];
            #pragma unroll
            for (int j = 0; j < MAXC; ++j)
                if (j < nc) {
                    short8 af = *(const short8*)(aptr + (cs + j) * 32);
                    acc = __builtin_amdgcn_mfma_f32_16x16x32_bf16(af, breg[j], acc, 0, 0, 0);
                }
        }

        // ---- phase 3: reduce k-splits, bias (+ReLU), store ----
        if (q > 0) pc[(w - NT) * 64 + f] = acc;
        barrier_lgkm();
        if (q == 0) {
            #pragma unroll
            for (int j = 1; j < S; ++j) {
                f32x4 p = pc[(t + NT * (j - 1)) * 64 + f];
                acc.x += p.x; acc.y += p.y; acc.z += p.z; acc.w += p.w;
            }
            const int col = f & 15;
            const int mrow = (f >> 4) * 4;   // C/D: row=(lane>>4)*4+reg
            #pragma unroll
            for (int i = 0; i < 4; ++i) {
                float v = acc[i] + bcol;
                if (RELU) v = fmaxf(v, 0.0f);
                size_t oi = (size_t)(node0 + mrow + i) * NOUT + n0 + col;
                if constexpr (sizeof(OutT) == 2) out[oi] = (OutT)f2b(v);
                else                             out[oi] = (OutT)v;
            }
        }

        // ---- tail: next-tile stripe + data-window prefetch ----
        if (more) {
            const int tot = nend - nstart;
            const int eb = tot >> 3, er = tot & 7;
            i0 = nstart + w * eb + (w < er ? w : er);
            i1 = i0 + eb + (w < er ? 1 : 0);
            w0v = 0xFF; wm0 = 0; w1v = 0xFF; wm1 = 0;
            int r0 = i0 + f;
            if (r0 < nend) { w0v = ssrc[r0]; if (i0 > nstart) wm0 = ssrc[r0 - 1]; }
            int r1 = i1 + f;
            if (r1 < nend && i1 < nend) { w1v = ssrc[r1]; if (i1 > nstart) wm1 = ssrc[r1 - 1]; }
        }
        startv = nstart; endv = nend; cvp = ncv; rootp = nroot;
        barrier_lgkm();   // protect a32/pc reuse before next zeroing
    }
}

#undef BATCH16

// ---------------------------------------------------------------------------
// Launch: 7 dispatches (memset, hist+prep, scanA, scanC, scat, layer1, layer2)
// ---------------------------------------------------------------------------
extern "C" void kernel_launch(void* const* d_in, const int* in_sizes, int n_in,
                              void* d_out, int out_size, void* d_ws, size_t ws_size,
                              hipStream_t stream) {
    const float* x     = (const float*)d_in[0];
    const int*   ei    = (const int*)d_in[1];
    const int*   et    = (const int*)d_in[2];
    const float* W1    = (const float*)d_in[3];
    const float* root1 = (const float*)d_in[4];
    const float* b1    = (const float*)d_in[5];
    const float* W2    = (const float*)d_in[6];
    const float* root2 = (const float*)d_in[7];
    const float* b2    = (const float*)d_in[8];
    float* out = (float*)d_out;

    const int* src = ei;            // edge_index[0]
    const int* dst = ei + N_EDGES;  // edge_index[1]

    // Workspace layout (~38.5 MB):
    //   cnt 3.2M | offs 3.2M | bsums 4K | ssrc 6.4M | xb 12.8M |
    //   h1b 12.8M (rank overlaps its first 6.4M — dead before h1b written) |
    //   Wt1b 73.7K | Wt2b 36.9K
    char* ws = (char*)d_ws;
    int*    cnt   = (int*)(ws);
    int*    offs  = (int*)(ws + (size_t)NSEG * 4);
    int*    bsums = (int*)(ws + (size_t)NSEG * 8);
    int*    ssrc  = (int*)(ws + (size_t)NSEG * 8 + 4096);
    ushort* xb    = (ushort*)(ws + (size_t)NSEG * 8 + 4096 + (size_t)N_EDGES * 4);
    ushort* h1b   = (ushort*)((char*)xb + (size_t)N_NODES * 64 * 2);
    int*    rank  = (int*)h1b;   // overlap: rank dead after k_scat
    ushort* Wt1b  = (ushort*)((char*)h1b + (size_t)N_NODES * 64 * 2);
    ushort* Wt2b  = (ushort*)((char*)Wt1b + (size_t)PREP_W1 * 2);

    (void)hipMemsetAsync(cnt, 0, (size_t)NSEG * 4, stream);

    int eb = (N_EDGES + 255) / 256;
    k_hist<<<eb, 256, 0, stream>>>(dst, et, cnt, rank,
                                   W1, root1, W2, root2, x, Wt1b, Wt2b, xb);
    k_scanA<<<SCAN_NB, 256, 0, stream>>>(cnt, bsums);
    k_scanC<<<SCAN_NB, 256, 0, stream>>>(cnt, bsums, offs);
    k_scat<<<eb, 256, 0, stream>>>(src, dst, et, offs, rank, ssrc);

    // Layer 1: xb -> h1b (bf16, ReLU), NOUT=64
    k_layer<64, true, ushort><<<LGRID, 512, 0, stream>>>(
        xb, offs, cnt, ssrc, Wt1b, b1, h1b);
    // Layer 2: h1b -> out (fp32), NOUT=32
    k_layer<32, false, float><<<LGRID, 512, 0, stream>>>(
        h1b, offs, cnt, ssrc, Wt2b, b2, out);
}